// Round 1
// baseline (175.593 us; speedup 1.0000x reference)
//
#include <hip/hip_runtime.h>
#include <hip/hip_bf16.h>

// HeadLayer: B=8, S=2048, E=1024, H=64.
// Inputs (fp32): x[B,S,E], Wq[E,H], Wk[E,H], Wv[E,H]. Output (fp32): [B,S,H].
// ws (bf16): qb[B,S,H] (pre-scaled 1/32), kb[B,S,H], vtb[B,H,S],
//            Wd[16][12][2][64] short8 frag-direct W layout (coalesced B loads).

#define BATCH 8
#define SEQ   2048
#define EMB   1024
#define HD    64
#define ROWS  (BATCH*SEQ)      // 16384
#define NTOT  192
#define BK    64
#define NKT   (EMB / BK)       // 16

typedef __attribute__((ext_vector_type(8))) short short8;   // 8 bf16 (4 VGPR)
typedef __attribute__((ext_vector_type(4))) float floatx4;  // MFMA C/D frag

static __device__ __forceinline__ short f2bf(float f) {
  union { __hip_bfloat16 h; short s; } u;
  u.h = __float2bfloat16(f);
  return u.s;
}

static __device__ __forceinline__ short8 pack8(float4 u, float4 v) {
  short8 r;
  r[0] = f2bf(u.x); r[1] = f2bf(u.y); r[2] = f2bf(u.z); r[3] = f2bf(u.w);
  r[4] = f2bf(v.x); r[5] = f2bf(v.y); r[6] = f2bf(v.z); r[7] = f2bf(v.w);
  return r;
}

// async global->LDS, 16 B per lane; LDS dest = wave-uniform base + lane*16
static __device__ __forceinline__ void gload_lds16(const void* g, void* l) {
  __builtin_amdgcn_global_load_lds(
      (const __attribute__((address_space(1))) unsigned int*)g,
      (__attribute__((address_space(3))) unsigned int*)l, 16, 0, 0);
}

// ---------------- W pre-pass: frag-direct layout -----------------------------
// Wd slot id = ((kt*12 + nt)*2 + ks)*64 + lane, holding short8:
//   value[u] = W_logical[nt*16 + (lane&15)][kt*64 + (4*ks + (lane>>4))*8 + u]
// so proj's B fragment bf[j][ks] is ONE coalesced short8 load per lane.
// W_logical[np][k] = Wsrc[k*HD + (np&63)], Wsrc = Wq/Wk/Wv by np range.
__global__ __launch_bounds__(256) void wt_kernel(
    const float* __restrict__ Wq, const float* __restrict__ Wk,
    const float* __restrict__ Wv, short* __restrict__ Wd) {
  const int id = blockIdx.x * 256 + threadIdx.x;   // 0..24575
  const int lane = id & 63;
  const int ks = (id >> 6) & 1;
  const int id2 = id >> 7;                          // kt*12 + nt, 0..191
  const int nt = id2 % 12;
  const int kt = id2 / 12;
  const int lo = lane & 15, quad = lane >> 4;
  const int np = nt * 16 + lo;                      // 0..191
  const float* __restrict__ W = (np < 64) ? Wq : ((np < 128) ? Wk : Wv);
  const int n = np & 63;
  const int k0 = kt * BK + (4 * ks + quad) * 8;
  short8 o;
#pragma unroll
  for (int u = 0; u < 8; ++u) o[u] = f2bf(W[(size_t)(k0 + u) * HD + n]);
  *(short8*)(Wd + (size_t)id * 8) = o;
}

// ---------------- MFMA QKV projection: 2-phase dbuf, B in registers ---------
// Grid 512 (2 blocks/CU). Block = 32 rows x 192 cols, full K.
// Per kt: ONE barrier; then async-stage A(kt+1) into As[buf^1] (2x
// global_load_lds w=16) + prefetch B(kt+1) into regs (6 coalesced short8 from
// L2-hot Wd); then frags+12 MFMA on buf. Stage latency hides under compute.
// B never touches LDS (wave-private tiles). LDS = 16 KB.
__global__ __launch_bounds__(256, 2) void proj_kernel(
    const float* __restrict__ x, const short* __restrict__ Wd,
    short* __restrict__ qb, short* __restrict__ kb_, short* __restrict__ vtb) {
  __shared__ __align__(16) float As[2][32 * 64];   // 16 KB

  const int t = threadIdx.x, lane = t & 63, w = t >> 6;
  const int lo = lane & 15, quad = lane >> 4;
  const int e = lo & 7;
  const int m0 = blockIdx.x * 32;

  // A staging: 2 chunks/wave, chunk = 4 rows x 256 B; lane -> row,slot
  const int cc0 = w * 2, cc1 = cc0 + 1;
  const int ar0 = cc0 * 4 + quad;
  const int ar1 = cc1 * 4 + quad;
  const float* agp0 = x + (size_t)(m0 + ar0) * EMB + ((lo ^ (ar0 & 7)) * 4);
  const float* agp1 = x + (size_t)(m0 + ar1) * EMB + ((lo ^ (ar1 & 7)) * 4);

  const short* bgp = Wd + (size_t)(w * 3) * 1024 + lane * 8;

  floatx4 acc[2][3];
#pragma unroll
  for (int mf = 0; mf < 2; ++mf)
#pragma unroll
    for (int j = 0; j < 3; ++j) acc[mf][j] = (floatx4){0.f, 0.f, 0.f, 0.f};

  short8 bcur[3][2], bnxt[3][2];

  auto STAGE_A = [&](int buf, int kt) {
    gload_lds16(agp0 + kt * BK, &As[buf][cc0 * 256]);
    gload_lds16(agp1 + kt * BK, &As[buf][cc1 * 256]);
  };
  auto LOAD_B = [&](short8 (&bf)[3][2], int kt) {
    const short* bg = bgp + (size_t)kt * 12288;
#pragma unroll
    for (int j = 0; j < 3; ++j)
#pragma unroll
      for (int ks = 0; ks < 2; ++ks)
        bf[j][ks] = *(const short8*)(bg + j * 1024 + ks * 512);
  };

  STAGE_A(0, 0);
  LOAD_B(bcur, 0);
  int buf = 0;
#pragma unroll
  for (int kt = 0; kt < NKT; ++kt) {
    __syncthreads();   // drains A(kt) stage; also fences reads of As[buf^1]
    if (kt + 1 < NKT) {
      STAGE_A(buf ^ 1, kt + 1);
      LOAD_B(bnxt, kt + 1);
    }
    // ---- A frags: row mf*16+lo, slots (8ks+2q+h)^e (2-way conflicts: free)
    short8 af[2][2];
#pragma unroll
    for (int mf = 0; mf < 2; ++mf) {
      const float* Ar = &As[buf][(mf * 16 + lo) * 64];
#pragma unroll
      for (int ks = 0; ks < 2; ++ks) {
        const float4 f0 = *(const float4*)(Ar + (((8 * ks + 2 * quad) ^ e) << 2));
        const float4 f1 = *(const float4*)(Ar + (((8 * ks + 2 * quad + 1) ^ e) << 2));
        af[mf][ks] = pack8(f0, f1);
      }
    }
#pragma unroll
    for (int ks = 0; ks < 2; ++ks)
#pragma unroll
      for (int j = 0; j < 3; ++j) {
        acc[0][j] = __builtin_amdgcn_mfma_f32_16x16x32_bf16(af[0][ks], bcur[j][ks], acc[0][j], 0, 0, 0);
        acc[1][j] = __builtin_amdgcn_mfma_f32_16x16x32_bf16(af[1][ks], bcur[j][ks], acc[1][j], 0, 0, 0);
      }
#pragma unroll
    for (int j = 0; j < 3; ++j)
#pragma unroll
      for (int ks = 0; ks < 2; ++ks) bcur[j][ks] = bnxt[j][ks];
    buf ^= 1;
  }

  // ---- epilogue: wave-private n-tiles, direct stores
  const int bb = m0 >> 11;
  const int sbase = (m0 & (SEQ - 1)) + quad * 4;
#pragma unroll
  for (int mf = 0; mf < 2; ++mf) {
    const int rowb = m0 + mf * 16 + quad * 4;
#pragma unroll
    for (int j = 0; j < 3; ++j) {
      const int nt = w * 3 + j;
      const floatx4 v = acc[mf][j];
      if (nt < 4) {
#pragma unroll
        for (int r = 0; r < 4; ++r)
          qb[(size_t)(rowb + r) * HD + nt * 16 + lo] = f2bf(v[r] * 0.03125f);
      } else if (nt < 8) {
#pragma unroll
        for (int r = 0; r < 4; ++r)
          kb_[(size_t)(rowb + r) * HD + (nt - 4) * 16 + lo] = f2bf(v[r]);
      } else {
        const int col = (nt - 8) * 16 + lo;
        short4 sv = make_short4(f2bf(v[0]), f2bf(v[1]), f2bf(v[2]), f2bf(v[3]));
        *(short4*)(vtb + ((size_t)bb * HD + col) * SEQ + sbase + mf * 16) = sv;
      }
    }
  }
}

// ---------------- MFMA flash attention: barrier-free, K/V direct from L2 ----
// K/V per batch = 256 KB each (L2/L3-resident) -> no LDS staging (guide
// common-mistake #7). Each wave loads its own K/V frags from global with
// 1-deep register prefetch; zero __syncthreads in the main loop, so waves
// desync -> s_setprio around MFMA clusters applies (m191).
#define PSTR 40

__global__ __launch_bounds__(256, 2) void attn_kernel(
    const short* __restrict__ qb, const short* __restrict__ kb,
    const short* __restrict__ vtb, float* __restrict__ out) {
  __shared__ __align__(16) short Ps[4][16 * PSTR];   // 5.1 KB (per-wave)
  __shared__ __align__(16) floatx4 Red[2][5][64];    // 10.2 KB

  const int b = blockIdx.y;
  const int bx = blockIdx.x;
  const int qx = (bx & 1) ? (63 - (bx >> 1)) : (bx >> 1);  // pair light+heavy
  const int q0 = qx * 32;
  const int t = threadIdx.x, lane = t & 63, w = t >> 6;
  const int wr = w >> 1, wk = w & 1;
  const int lo = lane & 15, quad = lane >> 4;

  const short* qp = qb + ((size_t)b * SEQ + q0 + wr * 16 + lo) * HD + quad * 8;
  const short8 qf0 = *(const short8*)(qp);
  const short8 qf1 = *(const short8*)(qp + 32);

  const short* __restrict__ kgb = kb + (size_t)b * SEQ * HD;
  const short* __restrict__ vgb = vtb + (size_t)b * HD * SEQ;
  // frag base addrs (wave collectively covers full 128 B rows)
  const short* kbase = kgb + (size_t)(wk * 32 + lo) * HD + quad * 8;
  const short* vbase = vgb + (size_t)lo * SEQ + wk * 32 + quad * 8;

  floatx4 acc[4];
  float lsum[4] = {0.f, 0.f, 0.f, 0.f};
#pragma unroll
  for (int nt = 0; nt < 4; ++nt) acc[nt] = (floatx4){0.f, 0.f, 0.f, 0.f};

  auto LOAD = [&](short8 (&kf)[2][2], short8 (&vf)[4], int j0) {
    const short* kp = kbase + (size_t)j0 * HD;
#pragma unroll
    for (int n2 = 0; n2 < 2; ++n2) {
      kf[n2][0] = *(const short8*)(kp + n2 * (16 * HD));
      kf[n2][1] = *(const short8*)(kp + n2 * (16 * HD) + 32);
    }
    const short* vp = vbase + j0;
#pragma unroll
    for (int nt = 0; nt < 4; ++nt)
      vf[nt] = *(const short8*)(vp + (size_t)(nt * 16) * SEQ);
  };

  short* Pw = Ps[w];
  const int rowb = q0 + wr * 16 + quad * 4;

  auto STEP = [&](short8 (&kf)[2][2], short8 (&vf)[4], int j0) {
    floatx4 s0 = (floatx4){0.f, 0.f, 0.f, 0.f};
    floatx4 s1 = (floatx4){0.f, 0.f, 0.f, 0.f};
    __builtin_amdgcn_s_setprio(1);
    s0 = __builtin_amdgcn_mfma_f32_16x16x32_bf16(qf0, kf[0][0], s0, 0, 0, 0);
    s0 = __builtin_amdgcn_mfma_f32_16x16x32_bf16(qf1, kf[0][1], s0, 0, 0, 0);
    s1 = __builtin_amdgcn_mfma_f32_16x16x32_bf16(qf0, kf[1][0], s1, 0, 0, 0);
    s1 = __builtin_amdgcn_mfma_f32_16x16x32_bf16(qf1, kf[1][1], s1, 0, 0, 0);
    __builtin_amdgcn_s_setprio(0);

    const bool diag = (j0 + 64 > q0);
#pragma unroll
    for (int r = 0; r < 4; ++r) {
      float e0 = __expf(s0[r]);
      float e1 = __expf(s1[r]);
      if (diag) {
        const int key0 = j0 + wk * 32 + lo;
        e0 = (key0 <= rowb + r) ? e0 : 0.f;
        e1 = (key0 + 16 <= rowb + r) ? e1 : 0.f;
      }
      lsum[r] += e0 + e1;
      Pw[(quad * 4 + r) * PSTR + lo] = f2bf(e0);
      Pw[(quad * 4 + r) * PSTR + 16 + lo] = f2bf(e1);
    }
    const short8 pf = *(const short8*)(&Pw[lo * PSTR + quad * 8]);
    __builtin_amdgcn_s_setprio(1);
#pragma unroll
    for (int nt = 0; nt < 4; ++nt)
      acc[nt] = __builtin_amdgcn_mfma_f32_16x16x32_bf16(pf, vf[nt], acc[nt], 0, 0, 0);
    __builtin_amdgcn_s_setprio(0);
  };

  const int niter = q0 / 64 + 1;
  short8 kA[2][2], vA[4], kB[2][2], vB[4];
  LOAD(kA, vA, 0);
  int it = 0;
  while (true) {
    if (it + 1 < niter) LOAD(kB, vB, (it + 1) * 64);   // prefetch ∥ STEP(A)
    STEP(kA, vA, it * 64);
    ++it; if (it >= niter) break;
    if (it + 1 < niter) LOAD(kA, vA, (it + 1) * 64);   // prefetch ∥ STEP(B)
    STEP(kB, vB, it * 64);
    ++it; if (it >= niter) break;
  }

#pragma unroll
  for (int d = 1; d < 16; d <<= 1) {
#pragma unroll
    for (int r = 0; r < 4; ++r) lsum[r] += __shfl_xor(lsum[r], d);
  }

  if (wk == 1) {
#pragma unroll
    for (int nt = 0; nt < 4; ++nt) Red[wr][nt][lane] = acc[nt];
    Red[wr][4][lane] = (floatx4){lsum[0], lsum[1], lsum[2], lsum[3]};
  }
  __syncthreads();
  if (wk == 0) {
    const floatx4 lp = Red[wr][4][lane];
    float invd[4];
#pragma unroll
    for (int r = 0; r < 4; ++r) invd[r] = 1.0f / (lsum[r] + lp[r]);
#pragma unroll
    for (int nt = 0; nt < 4; ++nt) {
      const floatx4 o = acc[nt] + Red[wr][nt][lane];
#pragma unroll
      for (int r = 0; r < 4; ++r)
        out[((size_t)b * SEQ + rowb + r) * HD + nt * 16 + lo] = o[r] * invd[r];
    }
  }
}

extern "C" void kernel_launch(void* const* d_in, const int* in_sizes, int n_in,
                              void* d_out, int out_size, void* d_ws, size_t ws_size,
                              hipStream_t stream) {
  const float* x  = (const float*)d_in[0];
  const float* Wq = (const float*)d_in[1];
  const float* Wk = (const float*)d_in[2];
  const float* Wv = (const float*)d_in[3];
  float* out = (float*)d_out;
  short* ws = (short*)d_ws;
  short* qbp = ws;
  short* kbp = ws + (size_t)ROWS * HD;
  short* vtp = ws + (size_t)2 * ROWS * HD;
  short* Wd  = ws + (size_t)3 * ROWS * HD;   // 384 KB; total 6.68 MB <= ws_size

  wt_kernel<<<dim3(96), 256, 0, stream>>>(Wq, Wk, Wv, Wd);
  proj_kernel<<<dim3(ROWS / 32), 256, 0, stream>>>(x, Wd, qbp, kbp, vtp);
  attn_kernel<<<dim3(SEQ / 32, BATCH), 256, 0, stream>>>(qbp, kbp, vtp, out);
}

// Round 2
// 163.229 us; speedup vs baseline: 1.0757x; 1.0757x over previous
//
#include <hip/hip_runtime.h>
#include <hip/hip_bf16.h>

// HeadLayer: B=8, S=2048, E=1024, H=64.
// Inputs (fp32): x[B,S,E], Wq[E,H], Wk[E,H], Wv[E,H]. Output (fp32): [B,S,H].
// ws: qb[B,S,H] bf16 (pre-scaled 1/32), kb[B,S,H] bf16, vtb[B,H,S] bf16,
//     Wd frag-direct W layout (bf16), pacc[B,S,4,H] fp32, plsum[B,S,4] fp32.

#define BATCH 8
#define SEQ   2048
#define EMB   1024
#define HD    64
#define ROWS  (BATCH*SEQ)      // 16384
#define BK    64
#define NKT   (EMB / BK)       // 16
#define NSPLIT 4

typedef __attribute__((ext_vector_type(8))) short short8;   // 8 bf16 (4 VGPR)
typedef __attribute__((ext_vector_type(4))) float floatx4;  // MFMA C/D frag

static __device__ __forceinline__ short f2bf(float f) {
  union { __hip_bfloat16 h; short s; } u;
  u.h = __float2bfloat16(f);
  return u.s;
}

static __device__ __forceinline__ short8 pack8(float4 u, float4 v) {
  short8 r;
  r[0] = f2bf(u.x); r[1] = f2bf(u.y); r[2] = f2bf(u.z); r[3] = f2bf(u.w);
  r[4] = f2bf(v.x); r[5] = f2bf(v.y); r[6] = f2bf(v.z); r[7] = f2bf(v.w);
  return r;
}

// ---------------- W pre-pass: frag-direct layout (unchanged, verified) ------
// Wd slot id = ((kt*12 + nt)*2 + ks)*64 + lane, holding short8:
//   value[u] = W_logical[nt*16 + (lane&15)][kt*64 + (4*ks + (lane>>4))*8 + u]
__global__ __launch_bounds__(256) void wt_kernel(
    const float* __restrict__ Wq, const float* __restrict__ Wk,
    const float* __restrict__ Wv, short* __restrict__ Wd) {
  const int id = blockIdx.x * 256 + threadIdx.x;   // 0..24575
  const int lane = id & 63;
  const int ks = (id >> 6) & 1;
  const int id2 = id >> 7;                          // kt*12 + nt
  const int nt = id2 % 12;
  const int kt = id2 / 12;
  const int lo = lane & 15, quad = lane >> 4;
  const int np = nt * 16 + lo;
  const float* __restrict__ W = (np < 64) ? Wq : ((np < 128) ? Wk : Wv);
  const int n = np & 63;
  const int k0 = kt * BK + (4 * ks + quad) * 8;
  short8 o;
#pragma unroll
  for (int u = 0; u < 8; ++u) o[u] = f2bf(W[(size_t)(k0 + u) * HD + n]);
  *(short8*)(Wd + (size_t)id * 8) = o;
}

// ---------------- MFMA QKV projection: reg-staged bf16 A, 1 barrier/kt ------
// Per kt: issue A(kt+1) global loads + B(kt+1) reg loads early; ds_read frags
// + 12 MFMA on buf; then convert A(kt+1) (8 f2bf/lane, was 32) and one
// ds_write_b128 to buf^1; barrier. A tile stored bf16 + XOR-swizzled.
__global__ __launch_bounds__(256, 2) void proj_kernel(
    const float* __restrict__ x, const short* __restrict__ Wd,
    short* __restrict__ qb, short* __restrict__ kb_, short* __restrict__ vtb) {
  __shared__ __align__(16) short Ab[2][32 * 64];   // 8 KB bf16, XOR-swizzled

  const int t = threadIdx.x, lane = t & 63, w = t >> 6;
  const int lo = lane & 15, quad = lane >> 4;
  const int e = lo & 7;
  const int m0 = blockIdx.x * 32;

  // staging: thread -> (row = t>>3, source k-chunk = t&7), store chunk at c^(row&7)
  const int srow = t >> 3, sc = t & 7;
  const float* sgp = x + (size_t)(m0 + srow) * EMB + sc * 8;
  const int sslot = srow * 64 + ((sc ^ (srow & 7)) << 3);

  const short* bgp = Wd + (size_t)(w * 3) * 1024 + lane * 8;

  floatx4 acc[2][3];
#pragma unroll
  for (int mf = 0; mf < 2; ++mf)
#pragma unroll
    for (int j = 0; j < 3; ++j) acc[mf][j] = (floatx4){0.f, 0.f, 0.f, 0.f};

  short8 bcur[3][2], bnxt[3][2];
  float4 ra, rb;

  auto LOADA = [&](int kt) {
    const float* p = sgp + kt * BK;
    ra = *(const float4*)(p);
    rb = *(const float4*)(p + 4);
  };
  auto LOAD_B = [&](short8 (&bf)[3][2], int kt) {
    const short* bg = bgp + (size_t)kt * 12288;
#pragma unroll
    for (int j = 0; j < 3; ++j)
#pragma unroll
      for (int ks = 0; ks < 2; ++ks)
        bf[j][ks] = *(const short8*)(bg + j * 1024 + ks * 512);
  };

  LOADA(0);
  LOAD_B(bcur, 0);
  *(short8*)(&Ab[0][sslot]) = pack8(ra, rb);
  __syncthreads();

  int buf = 0;
  for (int kt = 0; kt < NKT; ++kt) {
    const bool more = (kt + 1 < NKT);
    if (more) { LOADA(kt + 1); LOAD_B(bnxt, kt + 1); }
    // A frags: row mf*16+lo, k-chunk (4ks+quad)^e  (bf16, direct short8 reads)
    short8 af[2][2];
#pragma unroll
    for (int mf = 0; mf < 2; ++mf)
#pragma unroll
      for (int ks = 0; ks < 2; ++ks)
        af[mf][ks] = *(const short8*)(
            &Ab[buf][(mf * 16 + lo) * 64 + (((4 * ks + quad) ^ e) << 3)]);
#pragma unroll
    for (int ks = 0; ks < 2; ++ks)
#pragma unroll
      for (int j = 0; j < 3; ++j) {
        acc[0][j] = __builtin_amdgcn_mfma_f32_16x16x32_bf16(af[0][ks], bcur[j][ks], acc[0][j], 0, 0, 0);
        acc[1][j] = __builtin_amdgcn_mfma_f32_16x16x32_bf16(af[1][ks], bcur[j][ks], acc[1][j], 0, 0, 0);
      }
    if (more) {
      *(short8*)(&Ab[buf ^ 1][sslot]) = pack8(ra, rb);
#pragma unroll
      for (int j = 0; j < 3; ++j)
#pragma unroll
        for (int ks = 0; ks < 2; ++ks) bcur[j][ks] = bnxt[j][ks];
    }
    __syncthreads();
    buf ^= 1;
  }

  // ---- epilogue: wave-private n-tiles, direct stores (unchanged, verified)
  const int bb = m0 >> 11;
  const int sbase = (m0 & (SEQ - 1)) + quad * 4;
#pragma unroll
  for (int mf = 0; mf < 2; ++mf) {
    const int rowb = m0 + mf * 16 + quad * 4;
#pragma unroll
    for (int j = 0; j < 3; ++j) {
      const int nt = w * 3 + j;
      const floatx4 v = acc[mf][j];
      if (nt < 4) {
#pragma unroll
        for (int r = 0; r < 4; ++r)
          qb[(size_t)(rowb + r) * HD + nt * 16 + lo] = f2bf(v[r] * 0.03125f);
      } else if (nt < 8) {
#pragma unroll
        for (int r = 0; r < 4; ++r)
          kb_[(size_t)(rowb + r) * HD + (nt - 4) * 16 + lo] = f2bf(v[r]);
      } else {
        const int col = (nt - 8) * 16 + lo;
        short4 sv = make_short4(f2bf(v[0]), f2bf(v[1]), f2bf(v[2]), f2bf(v[3]));
        *(short4*)(vtb + ((size_t)bb * HD + col) * SEQ + sbase + mf * 16) = sv;
      }
    }
  }
}

// ---------------- split-K flash attention: partials to workspace ------------
// Grid (64*NSPLIT, BATCH) = 2048 blocks -> ~8 blocks/CU; launch_bounds(256,6)
// (VGPR<=85, LDS 15.4KB*6=92KB). Key tiles [sp*n/4, (sp+1)*n/4). No in-loop
// barriers; K/V frags direct from L2 (256KB/batch, resident); TLP hides
// latency. Writes un-normalized acc + lsum per split.
#define PSTR 40

__global__ __launch_bounds__(256, 6) void attn_kernel(
    const short* __restrict__ qb, const short* __restrict__ kb,
    const short* __restrict__ vtb, float* __restrict__ pacc,
    float* __restrict__ plsum) {
  __shared__ __align__(16) short Ps[4][16 * PSTR];   // 5.1 KB (per-wave)
  __shared__ __align__(16) floatx4 Red[2][5][64];    // 10.2 KB

  const int b = blockIdx.y;
  const int bx = blockIdx.x;
  const int qx = bx >> 2;
  const int sp = bx & 3;
  const int q0 = qx * 32;
  const int t = threadIdx.x, lane = t & 63, w = t >> 6;
  const int wr = w >> 1, wk = w & 1;
  const int lo = lane & 15, quad = lane >> 4;

  const int niter = q0 / 64 + 1;
  const int it0 = (sp * niter) >> 2;
  const int it1 = ((sp + 1) * niter) >> 2;

  const short* qp = qb + ((size_t)b * SEQ + q0 + wr * 16 + lo) * HD + quad * 8;
  const short8 qf0 = *(const short8*)(qp);
  const short8 qf1 = *(const short8*)(qp + 32);

  const short* __restrict__ kgb = kb + (size_t)b * SEQ * HD;
  const short* __restrict__ vgb = vtb + (size_t)b * HD * SEQ;
  const short* kbase = kgb + (size_t)(wk * 32 + lo) * HD + quad * 8;
  const short* vbase = vgb + (size_t)lo * SEQ + wk * 32 + quad * 8;

  floatx4 acc[4];
  float lsum[4] = {0.f, 0.f, 0.f, 0.f};
#pragma unroll
  for (int nt = 0; nt < 4; ++nt) acc[nt] = (floatx4){0.f, 0.f, 0.f, 0.f};

  short* Pw = Ps[w];
  const int rowb = q0 + wr * 16 + quad * 4;

  for (int it = it0; it < it1; ++it) {
    const int j0 = it * 64;
    short8 kf[2][2], vf[4];
    {
      const short* kp = kbase + (size_t)j0 * HD;
#pragma unroll
      for (int n2 = 0; n2 < 2; ++n2) {
        kf[n2][0] = *(const short8*)(kp + n2 * (16 * HD));
        kf[n2][1] = *(const short8*)(kp + n2 * (16 * HD) + 32);
      }
      const short* vp = vbase + j0;
#pragma unroll
      for (int nt = 0; nt < 4; ++nt)
        vf[nt] = *(const short8*)(vp + (size_t)(nt * 16) * SEQ);
    }

    floatx4 s0 = (floatx4){0.f, 0.f, 0.f, 0.f};
    floatx4 s1 = (floatx4){0.f, 0.f, 0.f, 0.f};
    __builtin_amdgcn_s_setprio(1);
    s0 = __builtin_amdgcn_mfma_f32_16x16x32_bf16(qf0, kf[0][0], s0, 0, 0, 0);
    s0 = __builtin_amdgcn_mfma_f32_16x16x32_bf16(qf1, kf[0][1], s0, 0, 0, 0);
    s1 = __builtin_amdgcn_mfma_f32_16x16x32_bf16(qf0, kf[1][0], s1, 0, 0, 0);
    s1 = __builtin_amdgcn_mfma_f32_16x16x32_bf16(qf1, kf[1][1], s1, 0, 0, 0);
    __builtin_amdgcn_s_setprio(0);

    const bool diag = (j0 + 64 > q0);
#pragma unroll
    for (int r = 0; r < 4; ++r) {
      float e0 = __expf(s0[r]);
      float e1 = __expf(s1[r]);
      if (diag) {
        const int key0 = j0 + wk * 32 + lo;
        e0 = (key0 <= rowb + r) ? e0 : 0.f;
        e1 = (key0 + 16 <= rowb + r) ? e1 : 0.f;
      }
      lsum[r] += e0 + e1;
      Pw[(quad * 4 + r) * PSTR + lo] = f2bf(e0);
      Pw[(quad * 4 + r) * PSTR + 16 + lo] = f2bf(e1);
    }
    const short8 pf = *(const short8*)(&Pw[lo * PSTR + quad * 8]);
    __builtin_amdgcn_s_setprio(1);
#pragma unroll
    for (int nt = 0; nt < 4; ++nt)
      acc[nt] = __builtin_amdgcn_mfma_f32_16x16x32_bf16(pf, vf[nt], acc[nt], 0, 0, 0);
    __builtin_amdgcn_s_setprio(0);
  }

#pragma unroll
  for (int d = 1; d < 16; d <<= 1) {
#pragma unroll
    for (int r = 0; r < 4; ++r) lsum[r] += __shfl_xor(lsum[r], d);
  }

  if (wk == 1) {
#pragma unroll
    for (int nt = 0; nt < 4; ++nt) Red[wr][nt][lane] = acc[nt];
    Red[wr][4][lane] = (floatx4){lsum[0], lsum[1], lsum[2], lsum[3]};
  }
  __syncthreads();
  if (wk == 0) {
    const floatx4 lp = Red[wr][4][lane];
#pragma unroll
    for (int nt = 0; nt < 4; ++nt) {
      const floatx4 o = acc[nt] + Red[wr][nt][lane];
#pragma unroll
      for (int r = 0; r < 4; ++r)
        pacc[(((size_t)b * SEQ + rowb + r) * NSPLIT + sp) * HD + nt * 16 + lo] = o[r];
    }
    if (lo == 0) {
#pragma unroll
      for (int r = 0; r < 4; ++r)
        plsum[((size_t)b * SEQ + rowb + r) * NSPLIT + sp] = lsum[r] + lp[r];
    }
  }
}

// ---------------- combine: out = sum(pacc)/sum(plsum) -----------------------
__global__ __launch_bounds__(256) void comb_kernel(
    const float* __restrict__ pacc, const float* __restrict__ plsum,
    float* __restrict__ out) {
  const int idx = blockIdx.x * 256 + threadIdx.x;   // 0 .. ROWS*16-1
  const int row = idx >> 4;
  const int h4 = (idx & 15) << 2;
  const float* pa = pacc + (size_t)row * (NSPLIT * HD) + h4;
  float4 s = make_float4(0.f, 0.f, 0.f, 0.f);
  float d = 0.f;
#pragma unroll
  for (int sp = 0; sp < NSPLIT; ++sp) {
    const float4 v = *(const float4*)(pa + sp * HD);
    s.x += v.x; s.y += v.y; s.z += v.z; s.w += v.w;
    d += plsum[(size_t)row * NSPLIT + sp];
  }
  const float inv = 1.0f / d;
  float4 o = make_float4(s.x * inv, s.y * inv, s.z * inv, s.w * inv);
  *(float4*)(out + (size_t)row * HD + h4) = o;
}

extern "C" void kernel_launch(void* const* d_in, const int* in_sizes, int n_in,
                              void* d_out, int out_size, void* d_ws, size_t ws_size,
                              hipStream_t stream) {
  const float* x  = (const float*)d_in[0];
  const float* Wq = (const float*)d_in[1];
  const float* Wk = (const float*)d_in[2];
  const float* Wv = (const float*)d_in[3];
  float* out = (float*)d_out;
  short* ws = (short*)d_ws;
  short* qbp = ws;
  short* kbp = ws + (size_t)ROWS * HD;
  short* vtp = ws + (size_t)2 * ROWS * HD;
  short* Wd  = ws + (size_t)3 * ROWS * HD;          // 24576*8 shorts (384 KB)
  float* pacc  = (float*)(ws + (size_t)3 * ROWS * HD + 196608);  // 16.8 MB
  float* plsum = pacc + (size_t)ROWS * NSPLIT * HD;              // 256 KB
  // total ws use ~23.7 MB

  wt_kernel<<<dim3(96), 256, 0, stream>>>(Wq, Wk, Wv, Wd);
  proj_kernel<<<dim3(ROWS / 32), 256, 0, stream>>>(x, Wd, qbp, kbp, vtp);
  attn_kernel<<<dim3(64 * NSPLIT, BATCH), 256, 0, stream>>>(qbp, kbp, vtp, pacc, plsum);
  comb_kernel<<<dim3(ROWS * 16 / 256), 256, 0, stream>>>(pacc, plsum, out);
}

// Round 3
// 152.626 us; speedup vs baseline: 1.1505x; 1.0695x over previous
//
#include <hip/hip_runtime.h>
#include <hip/hip_bf16.h>

// HeadLayer: B=8, S=2048, E=1024, H=64.
// Inputs (fp32): x[B,S,E], Wq[E,H], Wk[E,H], Wv[E,H]. Output (fp32): [B,S,H].
// ws: qb[B,S,H] bf16 (pre-scaled 1/32), kb[B,S,H] bf16, vtb[B,H,S] bf16,
//     Wd frag-direct W layout (bf16), pacc[B,S,4,H] fp32, plsum[B,S,4] fp32.

#define BATCH 8
#define SEQ   2048
#define EMB   1024
#define HD    64
#define ROWS  (BATCH*SEQ)      // 16384
#define BK    64
#define NKT   (EMB / BK)       // 16
#define NSPLIT 4

typedef __attribute__((ext_vector_type(8))) short short8;   // 8 bf16 (4 VGPR)
typedef __attribute__((ext_vector_type(4))) float floatx4;  // MFMA C/D frag

static __device__ __forceinline__ short f2bf(float f) {
  union { __hip_bfloat16 h; short s; } u;
  u.h = __float2bfloat16(f);
  return u.s;
}

static __device__ __forceinline__ short8 pack8(float4 u, float4 v) {
  short8 r;
  r[0] = f2bf(u.x); r[1] = f2bf(u.y); r[2] = f2bf(u.z); r[3] = f2bf(u.w);
  r[4] = f2bf(v.x); r[5] = f2bf(v.y); r[6] = f2bf(v.z); r[7] = f2bf(v.w);
  return r;
}

// ---------------- W pre-pass: frag-direct layout (unchanged, verified) ------
// Wd slot id = ((kt*12 + nt)*2 + ks)*64 + lane, holding short8:
//   value[u] = W_logical[nt*16 + (lane&15)][kt*64 + (4*ks + (lane>>4))*8 + u]
__global__ __launch_bounds__(256) void wt_kernel(
    const float* __restrict__ Wq, const float* __restrict__ Wk,
    const float* __restrict__ Wv, short* __restrict__ Wd) {
  const int id = blockIdx.x * 256 + threadIdx.x;   // 0..24575
  const int lane = id & 63;
  const int ks = (id >> 6) & 1;
  const int id2 = id >> 7;                          // kt*12 + nt
  const int nt = id2 % 12;
  const int kt = id2 / 12;
  const int lo = lane & 15, quad = lane >> 4;
  const int np = nt * 16 + lo;
  const float* __restrict__ W = (np < 64) ? Wq : ((np < 128) ? Wk : Wv);
  const int n = np & 63;
  const int k0 = kt * BK + (4 * ks + quad) * 8;
  short8 o;
#pragma unroll
  for (int u = 0; u < 8; ++u) o[u] = f2bf(W[(size_t)(k0 + u) * HD + n]);
  *(short8*)(Wd + (size_t)id * 8) = o;
}

// ---------------- MFMA QKV projection (unchanged from R2, verified) ---------
__global__ __launch_bounds__(256, 2) void proj_kernel(
    const float* __restrict__ x, const short* __restrict__ Wd,
    short* __restrict__ qb, short* __restrict__ kb_, short* __restrict__ vtb) {
  __shared__ __align__(16) short Ab[2][32 * 64];   // 8 KB bf16, XOR-swizzled

  const int t = threadIdx.x, lane = t & 63, w = t >> 6;
  const int lo = lane & 15, quad = lane >> 4;
  const int e = lo & 7;
  const int m0 = blockIdx.x * 32;

  const int srow = t >> 3, sc = t & 7;
  const float* sgp = x + (size_t)(m0 + srow) * EMB + sc * 8;
  const int sslot = srow * 64 + ((sc ^ (srow & 7)) << 3);

  const short* bgp = Wd + (size_t)(w * 3) * 1024 + lane * 8;

  floatx4 acc[2][3];
#pragma unroll
  for (int mf = 0; mf < 2; ++mf)
#pragma unroll
    for (int j = 0; j < 3; ++j) acc[mf][j] = (floatx4){0.f, 0.f, 0.f, 0.f};

  short8 bcur[3][2], bnxt[3][2];
  float4 ra, rb;

  auto LOADA = [&](int kt) {
    const float* p = sgp + kt * BK;
    ra = *(const float4*)(p);
    rb = *(const float4*)(p + 4);
  };
  auto LOAD_B = [&](short8 (&bf)[3][2], int kt) {
    const short* bg = bgp + (size_t)kt * 12288;
#pragma unroll
    for (int j = 0; j < 3; ++j)
#pragma unroll
      for (int ks = 0; ks < 2; ++ks)
        bf[j][ks] = *(const short8*)(bg + j * 1024 + ks * 512);
  };

  LOADA(0);
  LOAD_B(bcur, 0);
  *(short8*)(&Ab[0][sslot]) = pack8(ra, rb);
  __syncthreads();

  int buf = 0;
  for (int kt = 0; kt < NKT; ++kt) {
    const bool more = (kt + 1 < NKT);
    if (more) { LOADA(kt + 1); LOAD_B(bnxt, kt + 1); }
    short8 af[2][2];
#pragma unroll
    for (int mf = 0; mf < 2; ++mf)
#pragma unroll
      for (int ks = 0; ks < 2; ++ks)
        af[mf][ks] = *(const short8*)(
            &Ab[buf][(mf * 16 + lo) * 64 + (((4 * ks + quad) ^ e) << 3)]);
#pragma unroll
    for (int ks = 0; ks < 2; ++ks)
#pragma unroll
      for (int j = 0; j < 3; ++j) {
        acc[0][j] = __builtin_amdgcn_mfma_f32_16x16x32_bf16(af[0][ks], bcur[j][ks], acc[0][j], 0, 0, 0);
        acc[1][j] = __builtin_amdgcn_mfma_f32_16x16x32_bf16(af[1][ks], bcur[j][ks], acc[1][j], 0, 0, 0);
      }
    if (more) {
      *(short8*)(&Ab[buf ^ 1][sslot]) = pack8(ra, rb);
#pragma unroll
      for (int j = 0; j < 3; ++j)
#pragma unroll
        for (int ks = 0; ks < 2; ++ks) bcur[j][ks] = bnxt[j][ks];
    }
    __syncthreads();
    buf ^= 1;
  }

  const int bb = m0 >> 11;
  const int sbase = (m0 & (SEQ - 1)) + quad * 4;
#pragma unroll
  for (int mf = 0; mf < 2; ++mf) {
    const int rowb = m0 + mf * 16 + quad * 4;
#pragma unroll
    for (int j = 0; j < 3; ++j) {
      const int nt = w * 3 + j;
      const floatx4 v = acc[mf][j];
      if (nt < 4) {
#pragma unroll
        for (int r = 0; r < 4; ++r)
          qb[(size_t)(rowb + r) * HD + nt * 16 + lo] = f2bf(v[r] * 0.03125f);
      } else if (nt < 8) {
#pragma unroll
        for (int r = 0; r < 4; ++r)
          kb_[(size_t)(rowb + r) * HD + (nt - 4) * 16 + lo] = f2bf(v[r]);
      } else {
        const int col = (nt - 8) * 16 + lo;
        short4 sv = make_short4(f2bf(v[0]), f2bf(v[1]), f2bf(v[2]), f2bf(v[3]));
        *(short4*)(vtb + ((size_t)bb * HD + col) * SEQ + sbase + mf * 16) = sv;
      }
    }
  }
}

// ---------------- flash attention: 1 wave = 1 independent task --------------
// Wave task = (qt 16-row tile, batch, interleaved split sp: it = sp, sp+4,...).
// 32-key steps. No cross-wave coupling, zero barriers; per-wave P in LDS.
// Heavy tiles launch first (qt = 127 - bx>>3); splits in a block are equal
// length so blocks finish together. Rolling single-set prefetch: kf reloaded
// right after QK consumes it, vf right after PV -> next step's loads in
// flight ~a full step ahead. ~90 VGPR -> 16 waves/CU at launch_bounds(256,4).
#define PSTR 40

__global__ __launch_bounds__(256, 4) void attn_kernel(
    const short* __restrict__ qb, const short* __restrict__ kb,
    const short* __restrict__ vtb, float* __restrict__ pacc,
    float* __restrict__ plsum) {
  __shared__ __align__(16) short Ps[4][16 * PSTR];   // 5.1 KB, per-wave

  const int bx = blockIdx.x;                 // 0..1023
  const int qt = 127 - (bx >> 3);            // heavy first
  const int b = bx & 7;
  const int w = threadIdx.x >> 6;
  const int sp = w;                          // split = wave
  const int lane = threadIdx.x & 63;
  const int lo = lane & 15, quad = lane >> 4;
  const int q0 = qt * 16;
  const int niter = (qt >> 1) + 1;           // 32-key steps

  // Q frags: rows q0+lo, k-chunks quad*8 (+32)
  const short* qp = qb + ((size_t)b * SEQ + q0 + lo) * HD + quad * 8;
  const short8 qf0 = *(const short8*)(qp);
  const short8 qf1 = *(const short8*)(qp + 32);

  const short* __restrict__ kgb = kb + (size_t)b * SEQ * HD;
  const short* __restrict__ vgb = vtb + (size_t)b * HD * SEQ;

  floatx4 acc[4];
  float lsum[4] = {0.f, 0.f, 0.f, 0.f};
#pragma unroll
  for (int nt = 0; nt < 4; ++nt) acc[nt] = (floatx4){0.f, 0.f, 0.f, 0.f};

  short* Pw = Ps[w];
  const int rowq = q0 + quad * 4;            // q row base for s[.][r]

  const short* kp = kgb + (size_t)lo * HD + quad * 8 + (size_t)sp * 32 * HD;
  const short* vp = vgb + (size_t)lo * SEQ + quad * 8 + sp * 32;

  short8 kf[2][2], vf[4];
  auto LOADK = [&]() {
#pragma unroll
    for (int kt2 = 0; kt2 < 2; ++kt2)
#pragma unroll
      for (int ks = 0; ks < 2; ++ks)
        kf[kt2][ks] = *(const short8*)(kp + kt2 * 16 * HD + ks * 32);
  };
  auto LOADV = [&]() {
#pragma unroll
    for (int nt = 0; nt < 4; ++nt)
      vf[nt] = *(const short8*)(vp + (size_t)nt * 16 * SEQ);
  };

  int it = sp;
  if (it < niter) { LOADK(); LOADV(); }
  for (; it < niter; it += NSPLIT) {
    const int j0 = it * 32;
    // ---- QK^T (kf in regs)
    floatx4 s0 = (floatx4){0.f, 0.f, 0.f, 0.f};
    floatx4 s1 = (floatx4){0.f, 0.f, 0.f, 0.f};
    __builtin_amdgcn_s_setprio(1);
    s0 = __builtin_amdgcn_mfma_f32_16x16x32_bf16(qf0, kf[0][0], s0, 0, 0, 0);
    s0 = __builtin_amdgcn_mfma_f32_16x16x32_bf16(qf1, kf[0][1], s0, 0, 0, 0);
    s1 = __builtin_amdgcn_mfma_f32_16x16x32_bf16(qf0, kf[1][0], s1, 0, 0, 0);
    s1 = __builtin_amdgcn_mfma_f32_16x16x32_bf16(qf1, kf[1][1], s1, 0, 0, 0);
    __builtin_amdgcn_s_setprio(0);
    // ---- prefetch next K (kf regs free after QK issue)
    const bool more = (it + NSPLIT < niter);
    kp += NSPLIT * 32 * HD;
    if (more) LOADK();
    // ---- softmax numerator + P to per-wave LDS
    const bool diag = (j0 + 32 > q0);
#pragma unroll
    for (int r = 0; r < 4; ++r) {
      float e0 = __expf(s0[r]);
      float e1 = __expf(s1[r]);
      if (diag) {
        e0 = (j0 + lo <= rowq + r) ? e0 : 0.f;
        e1 = (j0 + 16 + lo <= rowq + r) ? e1 : 0.f;
      }
      lsum[r] += e0 + e1;
      Pw[(quad * 4 + r) * PSTR + lo] = f2bf(e0);
      Pw[(quad * 4 + r) * PSTR + 16 + lo] = f2bf(e1);
    }
    const short8 pf = *(const short8*)(&Pw[lo * PSTR + quad * 8]);
    // ---- P·V
    __builtin_amdgcn_s_setprio(1);
#pragma unroll
    for (int nt = 0; nt < 4; ++nt)
      acc[nt] = __builtin_amdgcn_mfma_f32_16x16x32_bf16(pf, vf[nt], acc[nt], 0, 0, 0);
    __builtin_amdgcn_s_setprio(0);
    // ---- prefetch next V (vf regs free after PV issue)
    vp += NSPLIT * 32;
    if (more) LOADV();
  }

  // row-sum over the 16 key lanes (lo bits only; quad carries q)
#pragma unroll
  for (int d = 1; d < 16; d <<= 1) {
#pragma unroll
    for (int r = 0; r < 4; ++r) lsum[r] += __shfl_xor(lsum[r], d);
  }

  // un-normalized partials out (zeros for empty splits)
#pragma unroll
  for (int nt = 0; nt < 4; ++nt) {
#pragma unroll
    for (int r = 0; r < 4; ++r)
      pacc[(((size_t)b * SEQ + rowq + r) * NSPLIT + sp) * HD + nt * 16 + lo] =
          acc[nt][r];
  }
  if (lo == 0) {
#pragma unroll
    for (int r = 0; r < 4; ++r)
      plsum[((size_t)b * SEQ + rowq + r) * NSPLIT + sp] = lsum[r];
  }
}

// ---------------- combine: out = sum(pacc)/sum(plsum) -----------------------
__global__ __launch_bounds__(256) void comb_kernel(
    const float* __restrict__ pacc, const float* __restrict__ plsum,
    float* __restrict__ out) {
  const int idx = blockIdx.x * 256 + threadIdx.x;   // 0 .. ROWS*16-1
  const int row = idx >> 4;
  const int h4 = (idx & 15) << 2;
  const float* pa = pacc + (size_t)row * (NSPLIT * HD) + h4;
  float4 s = make_float4(0.f, 0.f, 0.f, 0.f);
  float d = 0.f;
#pragma unroll
  for (int sp = 0; sp < NSPLIT; ++sp) {
    const float4 v = *(const float4*)(pa + sp * HD);
    s.x += v.x; s.y += v.y; s.z += v.z; s.w += v.w;
    d += plsum[(size_t)row * NSPLIT + sp];
  }
  const float inv = 1.0f / d;
  float4 o = make_float4(s.x * inv, s.y * inv, s.z * inv, s.w * inv);
  *(float4*)(out + (size_t)row * HD + h4) = o;
}

extern "C" void kernel_launch(void* const* d_in, const int* in_sizes, int n_in,
                              void* d_out, int out_size, void* d_ws, size_t ws_size,
                              hipStream_t stream) {
  const float* x  = (const float*)d_in[0];
  const float* Wq = (const float*)d_in[1];
  const float* Wk = (const float*)d_in[2];
  const float* Wv = (const float*)d_in[3];
  float* out = (float*)d_out;
  short* ws = (short*)d_ws;
  short* qbp = ws;
  short* kbp = ws + (size_t)ROWS * HD;
  short* vtp = ws + (size_t)2 * ROWS * HD;
  short* Wd  = ws + (size_t)3 * ROWS * HD;          // 24576*8 shorts (384 KB)
  float* pacc  = (float*)(ws + (size_t)3 * ROWS * HD + 196608);  // 16.8 MB
  float* plsum = pacc + (size_t)ROWS * NSPLIT * HD;              // 256 KB

  wt_kernel<<<dim3(96), 256, 0, stream>>>(Wq, Wk, Wv, Wd);
  proj_kernel<<<dim3(ROWS / 32), 256, 0, stream>>>(x, Wd, qbp, kbp, vtp);
  attn_kernel<<<dim3(128 * 8), 256, 0, stream>>>(qbp, kbp, vtp, pacc, plsum);
  comb_kernel<<<dim3(ROWS * 16 / 256), 256, 0, stream>>>(pacc, plsum, out);
}